// Round 9
// baseline (102.617 us; speedup 1.0000x reference)
//
#include <hip/hip_runtime.h>

// STU layer: out[b,t,e] = sum_{k,d} phi[t,k] * C[b,t,k,d] * W[k,e,d],
//            C = cumsum_t(phi[t,k] * x[b,t,d])
// Fused: out = A @ WT^T (M=16384, Kdim=4096, N=256); A-tile built in LDS from
// cumsum chains seeded by chunk-prefix states U. Deep pipeline (T3/T4/T5):
// B triple-buffered via global_load_lds with counted vmcnt(8); x prefetched
// depth-2 into registers; A double-buffered. BM=128 x BN=256, 64x64 wave
// tiles (0.5 ds_read per MFMA), ks-split=2 via atomics.
// B=4, T=4096, D=256, K=16, chunk CH=16 (256 chunks/batch).

typedef __bf16 bf16x8 __attribute__((ext_vector_type(8)));
typedef float  f32x4  __attribute__((ext_vector_type(4)));
typedef unsigned short u16;
typedef unsigned int   u32;

__device__ static inline u16 f2bf(float f) {          // RNE f32->bf16
    unsigned int u = __float_as_uint(f);
    u = (u + 0x7fffu + ((u >> 16) & 1u)) >> 16;
    return (u16)u;
}

__device__ static inline void gload16(const void* g, void* l) {
    __builtin_amdgcn_global_load_lds((const __attribute__((address_space(1))) void*)g,
                                     (__attribute__((address_space(3))) void*)l, 16, 0, 0);
}

// ---------------- k0: WT[e][d*16+k] = bf16(W[k][e][d]) ----------------
__global__ __launch_bounds__(256) void k0_wt(const float* __restrict__ W, u16* __restrict__ WT) {
    const int e = blockIdx.x, d = threadIdx.x;
    union { u16 u[16]; uint4 v[2]; } ob;
#pragma unroll
    for (int k = 0; k < 16; ++k)
        ob.u[k] = f2bf(W[((size_t)k * 256 + e) * 256 + d]);
    uint4* dst = (uint4*)(WT + (size_t)e * 4096 + d * 16);
    dst[0] = ob.v[0]; dst[1] = ob.v[1];
}

// ---------------- k1: chunk sums U[b,c,d,k] = sum_{s in 16-chunk} phi*x ----------------
__global__ __launch_bounds__(256) void k1_sums(const float* __restrict__ x,
                                               const float* __restrict__ phi,
                                               float* __restrict__ U) {
    __shared__ float phis[256];
    const int tid = threadIdx.x;
    const int b = blockIdx.x, c = blockIdx.y;
    const int t0 = c * 16;
    phis[tid] = phi[t0 * 16 + tid];
    __syncthreads();
    float acc[16];
#pragma unroll
    for (int k = 0; k < 16; ++k) acc[k] = 0.f;
    for (int s = 0; s < 16; ++s) {
        const float xv = x[(size_t)((b << 12) + t0 + s) * 256 + tid];
        union { float f[16]; float4 v[4]; } pv;
#pragma unroll
        for (int j = 0; j < 4; ++j) pv.v[j] = *(const float4*)&phis[s * 16 + j * 4];
#pragma unroll
        for (int k = 0; k < 16; ++k) acc[k] = fmaf(pv.f[k], xv, acc[k]);
    }
    float4* Up = (float4*)(U + ((size_t)((b * 256 + c) * 256 + tid)) * 16);
    union { float f[16]; float4 v[4]; } ov;
#pragma unroll
    for (int k = 0; k < 16; ++k) ov.f[k] = acc[k];
#pragma unroll
    for (int j = 0; j < 4; ++j) Up[j] = ov.v[j];
}

// ---------------- k2: exclusive scan of U over c (in place), coalesced ----------------
__global__ __launch_bounds__(256) void k2_scan(float* __restrict__ U) {
    const int b  = blockIdx.x;                     // grid (4,64)
    const int dl = threadIdx.x & 63;
    const int dk = blockIdx.y * 64 + dl;
    const int q  = threadIdx.x >> 6;               // c-quarter 0..3
    float* base = U + (size_t)b * 1048576 + (size_t)(q * 64) * 4096 + dk;
    float s = 0.f;
#pragma unroll 8
    for (int j = 0; j < 64; ++j) s += base[(size_t)j * 4096];
    __shared__ float qs[4][64];
    qs[q][dl] = s;
    __syncthreads();
    float pre = 0.f;
#pragma unroll
    for (int i = 0; i < 4; ++i) pre += (i < q) ? qs[i][dl] : 0.f;
    float run = pre;
#pragma unroll 8
    for (int j = 0; j < 64; ++j) {
        const float v = base[(size_t)j * 4096];
        base[(size_t)j * 4096] = run;
        run += v;
    }
}

// ---------------- k4: fused A-build + GEMM, deep-pipelined, ks-split=2 ----------------
// BM=128, BN=256, BK=64, 32 K-steps/block, 512 thr = 8 waves (2M x 4N,
// 64x64 wave tiles). Waves 0-3: chain-build (2 chains/lane, depth 16).
// Waves 4-7: B staging (8 gload16 each). All: MFMA (32/step).
// LDS 128KB: B[3][32768] @0, A[2][16384] @98304.
__global__ __launch_bounds__(512, 2) void k4_fused(const float* __restrict__ x,
                                                   const float* __restrict__ phi,
                                                   const float* __restrict__ U,
                                                   const u16* __restrict__ BT,
                                                   float* __restrict__ C) {
    __shared__ __align__(16) char smem[131072];
    const int tid = threadIdx.x;
    const int m0 = blockIdx.x * 128;             // global row base (bt)
    const int ks = blockIdx.y;                   // kdim half 0/1
    const int b  = m0 >> 12, t0 = m0 & 4095, c0 = t0 >> 4;
    const int w = tid >> 6, l = tid & 63;
    const int wm = (w >> 2) * 64, wn = (w & 3) * 64;
    const int lg = l >> 4, lr = l & 15;
    f32x4 acc[4][4] = {};

    const bool is_chain = (w < 4);
    const bool is_stage = (w >= 4);

    // chain lane mapping: lane owns chains (ch, dl, k=2kp & 2kp+1), depth 16
    const int kp = l & 7, dl = (l >> 3) & 3, ch = (w << 1) | (l >> 5);  // ch 0..7
    const int colb = dl * 32 + kp * 4;           // A col byte (elem dl*16+2kp)
    float2 p01[16];
    if (is_chain) {
#pragma unroll
        for (int s = 0; s < 16; ++s)
            p01[s] = *(const float2*)&phi[(t0 + ch * 16 + s) * 16 + kp * 2];
    }

    // stage addressing (waves 4-7): row = c*32 + (tl>>3), col piece per kt
    const int tl = tid & 255;
    const char* bsrc = (const char*)BT + (size_t)(tl >> 3) * 8192 + ks * 4096
                     + (((tl & 7) * 16) ^ (((tl >> 3) & 7) << 4));
    char* const smemA = smem + 98304;

    auto stageB = [&](int kt, int bufw) {
        char* dst = smem + bufw * 32768 + tl * 16;
        const char* src = bsrc + (size_t)kt * 128;
#pragma unroll
        for (int c = 0; c < 8; ++c)
            gload16(src + (size_t)c * 262144, dst + c * 4096);
    };
    auto issueX = [&](float (&xr)[16], float2& us, int kt) {
        const int d = ks * 128 + kt * 4 + dl;
        const float* xp = x + (size_t)(m0 + ch * 16) * 256 + d;
#pragma unroll
        for (int s = 0; s < 16; ++s) xr[s] = xp[(size_t)s * 256];
        us = *(const float2*)&U[((size_t)((b * 256 + c0 + ch) * 256 + d)) * 16 + kp * 2];
    };
    auto chains = [&](const float (&xr)[16], float2 us, int abw) {
        float r0 = us.x, r1 = us.y;
        char* Ab = smemA + abw * 16384 + ch * 2048;
#pragma unroll
        for (int s = 0; s < 16; ++s) {
            r0 = fmaf(p01[s].x, xr[s], r0);
            r1 = fmaf(p01[s].y, xr[s], r1);
            const float v0 = p01[s].x * r0, v1 = p01[s].y * r1;
            u32 pk;
            asm("v_cvt_pk_bf16_f32 %0, %1, %2" : "=v"(pk) : "v"(v0), "v"(v1));
            *(u32*)(Ab + s * 128 + (colb ^ ((s & 7) << 4))) = pk;
        }
    };
    auto mfma_phase = [&](int abr, int bbr) {
        const char* Abase = smemA + abr * 16384;
        const char* Bbase = smem + bbr * 32768;
#pragma unroll
        for (int kk = 0; kk < 2; ++kk) {
            const int kb = kk * 64 + lg * 16;
            bf16x8 af[4], bfv[4];
#pragma unroll
            for (int mi = 0; mi < 4; ++mi) {
                const int r = wm + mi * 16 + lr;
                af[mi] = *(const bf16x8*)(Abase + r * 128 + (kb ^ ((r & 7) << 4)));
            }
#pragma unroll
            for (int ni = 0; ni < 4; ++ni) {
                const int n = wn + ni * 16 + lr;
                bfv[ni] = *(const bf16x8*)(Bbase + n * 128 + (kb ^ ((n & 7) << 4)));
            }
#pragma unroll
            for (int mi = 0; mi < 4; ++mi)
#pragma unroll
                for (int ni = 0; ni < 4; ++ni)
                    acc[mi][ni] = __builtin_amdgcn_mfma_f32_16x16x32_bf16(af[mi], bfv[ni], acc[mi][ni], 0, 0, 0);
        }
    };

    // ---- prologue: B(0)->buf0, B(1)->buf1 in flight; x(0),x(1) in regs; A(0)
    float xA[16], xB[16]; float2 uA, uB;
    if (is_chain) { issueX(xA, uA, 0); issueX(xB, uB, 1); }
    if (is_stage) { stageB(0, 0); stageB(1, 1); }
    __builtin_amdgcn_sched_barrier(0);
    if (is_chain) {
        chains(xA, uA, 0);
        asm volatile("s_waitcnt lgkmcnt(0)" ::: "memory");
    }
    if (is_stage) asm volatile("s_waitcnt vmcnt(8)" ::: "memory");  // B(0) done
    asm volatile("s_barrier" ::: "memory");

    int br = 0, bw = 2;
    // per-step: issue(kt+2) | chains(kt+1) | MFMA(kt) | counted waits | barrier
    auto body = [&](int kt, float (&xW)[16], float2& uW,
                    const float (&xR)[16], float2 uR) {
        const int abr = kt & 1;
        if (kt + 2 < 32) {
            if (is_stage)      stageB(kt + 2, bw);
            else if (is_chain) issueX(xW, uW, kt + 2);
        }
        __builtin_amdgcn_sched_barrier(0);
        if (is_chain && (kt + 1 < 32)) chains(xR, uR, abr ^ 1);
        __builtin_amdgcn_s_setprio(1);
        mfma_phase(abr, br);
        __builtin_amdgcn_s_setprio(0);
        if (is_chain) asm volatile("s_waitcnt lgkmcnt(0)" ::: "memory");
        if (is_stage) {
            if (kt + 2 < 32) asm volatile("s_waitcnt vmcnt(8)" ::: "memory");
            else             asm volatile("s_waitcnt vmcnt(0)" ::: "memory");
        }
        if (kt < 31) asm volatile("s_barrier" ::: "memory");
        br = (br == 2) ? 0 : br + 1;
        bw = (bw == 2) ? 0 : bw + 1;
    };

    for (int kt = 0; kt < 32; kt += 2) {
        body(kt,     xA, uA, xB, uB);            // even: write xA, read xB
        body(kt + 1, xB, uB, xA, uA);            // odd : write xB, read xA
    }

    // ---- epilogue: two contributions per element (ks=0/1), commutative f32 adds
#pragma unroll
    for (int mi = 0; mi < 4; ++mi)
#pragma unroll
        for (int ni = 0; ni < 4; ++ni)
#pragma unroll
            for (int r = 0; r < 4; ++r) {
                const int row = m0 + wm + mi * 16 + lg * 4 + r;
                const int col = wn + ni * 16 + lr;
                unsafeAtomicAdd(&C[(size_t)row * 256 + col], acc[mi][ni][r]);
            }
}

extern "C" void kernel_launch(void* const* d_in, const int* in_sizes, int n_in,
                              void* d_out, int out_size, void* d_ws, size_t ws_size,
                              hipStream_t stream) {
    const float* x   = (const float*)d_in[0];   // (4,4096,256)
    const float* W   = (const float*)d_in[1];   // (16,256,256)
    const float* phi = (const float*)d_in[2];   // (4096,16)
    float* out = (float*)d_out;                 // (4,4096,256) f32

    char* ws = (char*)d_ws;
    u16*   WT = (u16*)ws;                       // 2 MB
    float* U  = (float*)(ws + (2u << 20));      // 16 MB

    k0_wt  <<<256, 256, 0, stream>>>(W, WT);
    k1_sums<<<dim3(4, 256), 256, 0, stream>>>(x, phi, U);
    k2_scan<<<dim3(4, 64), 256, 0, stream>>>(U);
    hipMemsetAsync(d_out, 0, (size_t)out_size * sizeof(float), stream);
    k4_fused<<<dim3(128, 2), 512, 0, stream>>>(x, phi, U, WT, out);
}